// Round 1
// baseline (224.617 us; speedup 1.0000x reference)
//
#include <hip/hip_runtime.h>

#define BB     4
#define T_IN   12
#define T_OUT  24
#define NNODES 5000
#define CC     32
#define HH     8
#define K1     17
#define O_OUT  12           // T_OUT - T_IN
#define BT     (BB * T_IN)  // 48

// ---------------- kernel 1: global max over nearest_dists ----------------
__global__ void max_reduce_kernel(const float* __restrict__ d, int n,
                                  unsigned* __restrict__ out) {
    float m = 0.0f;  // dists are uniform[0,100) -> nonnegative
    for (int i = blockIdx.x * blockDim.x + threadIdx.x; i < n;
         i += gridDim.x * blockDim.x)
        m = fmaxf(m, d[i]);
#pragma unroll
    for (int off = 32; off > 0; off >>= 1)
        m = fmaxf(m, __shfl_down(m, off, 64));
    if ((threadIdx.x & 63) == 0)
        atomicMax(out, __float_as_uint(m));  // bit-order == float order for >=0
}

// ---------------- kernel 2: out[:, :T_IN] = x ----------------
__global__ void copy_x_kernel(const float4* __restrict__ x,
                              float4* __restrict__ out) {
    const int PLANE = NNODES * CC / 4;  // 40000 float4 per (b,t) plane
    const int total = BT * PLANE;
    for (int i = blockIdx.x * blockDim.x + threadIdx.x; i < total;
         i += gridDim.x * blockDim.x) {
        int bt = i / PLANE;
        int q  = i - bt * PLANE;
        int b  = bt / T_IN;
        int t  = bt - b * T_IN;
        out[((size_t)(b * T_OUT + t)) * PLANE + q] = x[i];
    }
}

// ---------------- kernel 3: fused gather-aggregate-shrink-swish ----------------
__launch_bounds__(256)
__global__ void gnn_main_kernel(const float* __restrict__ x,
                                const int* __restrict__ nn,
                                const float* __restrict__ nd,
                                const float* __restrict__ Wsh,
                                const float* __restrict__ bsh,
                                const unsigned* __restrict__ maxbits,
                                float* __restrict__ out) {
    __shared__ float xbuf[2][BT][CC];      // 12 KB, double-buffered neighbor rows
    __shared__ float Wl[96][O_OUT];        // 4.5 KB
    __shared__ float bl[O_OUT];
    __shared__ float wl[K1][HH];           // GCN weights for this node
    __shared__ int   nnl[K1];
    __shared__ float part[8][O_OUT][CC];   // 12 KB, per-btg partial y

    const int n   = blockIdx.x;
    const int tid = threadIdx.x;
    const int btg = tid >> 5;        // 0..7 : which group of 6 bt-slots
    const int c   = tid & 31;        // channel
    const int t0  = (btg & 1) * 6;   // time offset within its b

    // --- stage W_shrink + bias + neighbor meta ---
    for (int i = tid; i < 96 * O_OUT; i += 256) ((float*)Wl)[i] = Wsh[i];
    if (tid < O_OUT) bl[tid] = bsh[tid];
    if (tid < K1)    nnl[tid] = nn[n * K1 + tid];

    // --- per-(j,h) GCN weights ---
    {
        float mx    = __uint_as_float(*maxbits);
        float sigma = mx * 0.5f;                 // / SIGMA_RATIO
        float inv_s2 = 1.0f / (sigma * sigma);
        if (tid < K1 * HH) {
            int j = tid >> 3, h = tid & 7;
            float dv  = nd[n * K1 + j];
            float lam = (float)(h + 1) * (1.0f / HH);
            float wv  = expf(-dv * dv * lam * inv_s2);
            if (nn[n * K1 + j] == -1 || wv < 1e-5f) wv = 0.0f;
            wl[j][h] = wv;
        }
    }
    __syncthreads();

    // --- neighbor-row staging: 48*32 floats = 384 float4 ---
    auto stage = [&](int buf, int j) {
        int idx = nnl[j];
        float4* dstv = (float4*)&xbuf[buf][0][0];
        if (idx >= 0) {
            const float4* src = (const float4*)x;
            {
                int pos = tid, bt4 = pos >> 3, cq = pos & 7;
                dstv[pos] = src[(size_t)(bt4 * NNODES + idx) * 8 + cq];
            }
            if (tid < 128) {
                int pos = tid + 256, bt4 = pos >> 3, cq = pos & 7;
                dstv[pos] = src[(size_t)(bt4 * NNODES + idx) * 8 + cq];
            }
        } else {
            float4 z = make_float4(0.f, 0.f, 0.f, 0.f);
            dstv[tid] = z;
            if (tid < 128) dstv[tid + 256] = z;
        }
    };

    float acc[6][8];
#pragma unroll
    for (int i = 0; i < 6; ++i)
#pragma unroll
        for (int h = 0; h < 8; ++h) acc[i][h] = 0.f;

    stage(0, 0);
    __syncthreads();

    for (int j = 0; j < K1; ++j) {
        int cur = j & 1;
        if (j + 1 < K1) stage(cur ^ 1, j + 1);

        float wv[8];
#pragma unroll
        for (int h = 0; h < 8; ++h) wv[h] = wl[j][h];
#pragma unroll
        for (int i = 0; i < 6; ++i) {
            float xv = xbuf[cur][btg * 6 + i][c];
#pragma unroll
            for (int h = 0; h < 8; ++h) acc[i][h] = fmaf(wv[h], xv, acc[i][h]);
        }
        __syncthreads();
    }

    // --- fold acc into per-o partials against W_shrink ---
    float p[O_OUT];
#pragma unroll
    for (int o = 0; o < O_OUT; ++o) p[o] = 0.f;
#pragma unroll
    for (int i = 0; i < 6; ++i) {
#pragma unroll
        for (int h = 0; h < 8; ++h) {
            float a = acc[i][h];
            const float* wr = &Wl[(t0 + i) * 8 + h][0];
#pragma unroll
            for (int o = 0; o < O_OUT; ++o) p[o] = fmaf(a, wr[o], p[o]);
        }
    }
#pragma unroll
    for (int o = 0; o < O_OUT; ++o) part[btg][o][c] = p[o];
    __syncthreads();

    // --- reduce btg pairs, bias, swish, write ---
#pragma unroll
    for (int k = 0; k < 6; ++k) {
        int idx = k * 256 + tid;        // 0..1535 : (b, o, c)
        int b   = idx / (O_OUT * CC);
        int r   = idx - b * (O_OUT * CC);
        int o   = r >> 5;
        int cc2 = r & 31;
        float v  = part[2 * b][o][cc2] + part[2 * b + 1][o][cc2] + bl[o];
        float sw = v / (1.0f + expf(-0.8f * v));
        out[(((size_t)b * T_OUT + T_IN + o) * NNODES + n) * CC + cc2] = sw;
    }
}

extern "C" void kernel_launch(void* const* d_in, const int* in_sizes, int n_in,
                              void* d_out, int out_size, void* d_ws, size_t ws_size,
                              hipStream_t stream) {
    const float* x   = (const float*)d_in[0];
    const int*   nn  = (const int*)d_in[1];
    const float* nd  = (const float*)d_in[2];
    const float* Wsh = (const float*)d_in[3];
    const float* bsh = (const float*)d_in[4];
    float* out = (float*)d_out;
    unsigned* maxbits = (unsigned*)d_ws;

    // zero the atomic-max slot (dists >= 0, so 0 bits == 0.0f is identity)
    hipMemsetAsync(d_ws, 0, sizeof(unsigned), stream);

    max_reduce_kernel<<<84, 256, 0, stream>>>(nd, NNODES * K1, maxbits);

    copy_x_kernel<<<2048, 256, 0, stream>>>((const float4*)x, (float4*)out);

    gnn_main_kernel<<<NNODES, 256, 0, stream>>>(x, nn, nd, Wsh, bsh, maxbits, out);
}

// Round 2
// 113.972 us; speedup vs baseline: 1.9708x; 1.9708x over previous
//
#include <hip/hip_runtime.h>

#define BB     4
#define T_IN   12
#define T_OUT  24
#define NNODES 5000
#define CC     32
#define HH     8
#define K1     17
#define O_OUT  12            // T_OUT - T_IN
#define XSTRIDE (NNODES*CC)  // 160000 floats per (b,t) plane (same for x and out)

// ---------------- kernel 1: global max over nearest_dists ----------------
__global__ void max_reduce_kernel(const float* __restrict__ d, int n,
                                  unsigned* __restrict__ out) {
    float m = 0.0f;  // dists are uniform[0,100) -> nonnegative
    for (int i = blockIdx.x * blockDim.x + threadIdx.x; i < n;
         i += gridDim.x * blockDim.x)
        m = fmaxf(m, d[i]);
#pragma unroll
    for (int off = 32; off > 0; off >>= 1)
        m = fmaxf(m, __shfl_down(m, off, 64));
    if ((threadIdx.x & 63) == 0)
        atomicMax(out, __float_as_uint(m));  // bit order == float order for >=0
}

// ---------------- kernel 2: fused copy + gather-aggregate-shrink-swish ----
// One block per node n. Thread layout: rg = tid>>4 (0..15), c2 = tid&15.
//   b = rg>>2 (batch), q = rg&3, rows t = 3q+{0,1,2}; channels {2c2, 2c2+1}.
// Wave w == batch b (lane = 16q + c2), so the q-reduction is shfl_xor(16/32).
__launch_bounds__(256, 4)
__global__ void gnn_main_kernel(const float* __restrict__ x,
                                const int* __restrict__ nn,
                                const float* __restrict__ nd,
                                const float* __restrict__ Wsh,
                                const float* __restrict__ bsh,
                                const unsigned* __restrict__ maxbits,
                                float* __restrict__ out) {
    __shared__ float wl[K1][HH];     // GCN weights (544 B)
    __shared__ float Wl[96][O_OUT];  // W_shrink (4.5 KB)
    __shared__ float bl_s[O_OUT];
    __shared__ int   nnl[K1];        // clamped neighbor indices

    const int n   = blockIdx.x;
    const int tid = threadIdx.x;
    const int rg  = tid >> 4;
    const int c2  = tid & 15;
    const int b   = rg >> 2;
    const int q   = rg & 3;

    // --- fused pass-through copy: out[b, t<12, n, :] = x[b, t, n, :] ---
    {
        const float* xs = x + (b * T_IN + 3 * q) * XSTRIDE + n * CC + 2 * c2;
        float* os = out + ((size_t)(b * T_OUT + 3 * q) * NNODES + n) * CC + 2 * c2;
        float2 r0 = *(const float2*)(xs);
        float2 r1 = *(const float2*)(xs + XSTRIDE);
        float2 r2 = *(const float2*)(xs + 2 * XSTRIDE);
        *(float2*)(os)               = r0;
        *(float2*)(os + XSTRIDE)     = r1;
        *(float2*)(os + 2 * XSTRIDE) = r2;
    }

    // --- stage W_shrink, bias, per-(j,h) GCN weights, neighbor indices ---
    for (int i = tid; i < 96 * O_OUT; i += 256) ((float*)Wl)[i] = Wsh[i];
    if (tid < O_OUT) bl_s[tid] = bsh[tid];
    if (tid < K1 * HH) {
        int j = tid >> 3, h = tid & 7;
        int v = nn[n * K1 + j];
        float dv = nd[n * K1 + j];
        float mx = __uint_as_float(*maxbits);
        float inv_s2 = 4.0f / (mx * mx);          // 1/sigma^2, sigma = mx/2
        float lam = (float)(h + 1) * 0.125f;
        float wv = expf(-dv * dv * lam * inv_s2);
        if (v == -1 || wv < 1e-5f) wv = 0.0f;
        wl[j][h] = wv;
    }
    if (tid < K1) nnl[tid] = max(nn[n * K1 + tid], 0);  // -1 -> 0 (weight already 0)
    __syncthreads();

    // --- barrier-free gather + aggregate, explicit 2-deep register pipeline ---
    float acc[3][2][8];
#pragma unroll
    for (int k = 0; k < 3; ++k)
#pragma unroll
        for (int cc = 0; cc < 2; ++cc)
#pragma unroll
            for (int h = 0; h < 8; ++h) acc[k][cc][h] = 0.f;

    const float* xbase = x + (b * T_IN + 3 * q) * XSTRIDE + 2 * c2;

    float2 xa0, xa1, xa2, xb0, xb1, xb2;

#define LOADJ(v0, v1, v2, J) do {                                            \
        int idx_ = __builtin_amdgcn_readfirstlane(nnl[(J)]);                 \
        const float* bp_ = xbase + idx_ * CC;                                \
        v0 = *(const float2*)(bp_);                                          \
        v1 = *(const float2*)(bp_ + XSTRIDE);                                \
        v2 = *(const float2*)(bp_ + 2 * XSTRIDE);                            \
    } while (0)

#define COMPJ(v0, v1, v2, J) do {                                            \
        float4 wA_ = *(const float4*)&wl[(J)][0];                            \
        float4 wB_ = *(const float4*)&wl[(J)][4];                            \
        float wv_[8] = {wA_.x, wA_.y, wA_.z, wA_.w,                          \
                        wB_.x, wB_.y, wB_.z, wB_.w};                         \
        float xv_[3][2] = {{v0.x, v0.y}, {v1.x, v1.y}, {v2.x, v2.y}};        \
        _Pragma("unroll")                                                    \
        for (int k_ = 0; k_ < 3; ++k_)                                       \
            _Pragma("unroll")                                                \
            for (int cc_ = 0; cc_ < 2; ++cc_)                                \
                _Pragma("unroll")                                            \
                for (int h_ = 0; h_ < 8; ++h_)                               \
                    acc[k_][cc_][h_] =                                       \
                        fmaf(wv_[h_], xv_[k_][cc_], acc[k_][cc_][h_]);       \
    } while (0)

    LOADJ(xa0, xa1, xa2, 0);
#pragma unroll 1
    for (int jj = 0; jj < 8; ++jj) {
        LOADJ(xb0, xb1, xb2, 2 * jj + 1);
        COMPJ(xa0, xa1, xa2, 2 * jj);
        LOADJ(xa0, xa1, xa2, 2 * jj + 2);   // jj=7 -> J=16 (tail prefetch)
        COMPJ(xb0, xb1, xb2, 2 * jj + 1);
    }
    COMPJ(xa0, xa1, xa2, 16);

#undef LOADJ
#undef COMPJ

    // --- fold acc against W_shrink: p[cc][o] = sum_{k,h} acc*W[(3q+k)*8+h][o]
    float p[2][O_OUT];
#pragma unroll
    for (int o = 0; o < O_OUT; ++o) { p[0][o] = 0.f; p[1][o] = 0.f; }

#pragma unroll
    for (int k = 0; k < 3; ++k) {
#pragma unroll
        for (int h = 0; h < 8; ++h) {
            int row = (3 * q + k) * 8 + h;           // runtime LDS addr: fine
            const float4* wr = (const float4*)&Wl[row][0];  // 48B rows, aligned
            float4 w0 = wr[0], w1 = wr[1], w2 = wr[2];
            float wrow[12] = {w0.x, w0.y, w0.z, w0.w,
                              w1.x, w1.y, w1.z, w1.w,
                              w2.x, w2.y, w2.z, w2.w};
            float a0 = acc[k][0][h], a1 = acc[k][1][h];
#pragma unroll
            for (int o = 0; o < O_OUT; ++o) {
                p[0][o] = fmaf(a0, wrow[o], p[0][o]);
                p[1][o] = fmaf(a1, wrow[o], p[1][o]);
            }
        }
    }

    // --- q-reduction via wave butterfly (wave == batch b) ---
#pragma unroll
    for (int cc = 0; cc < 2; ++cc)
#pragma unroll
        for (int o = 0; o < O_OUT; ++o) {
            float v = p[cc][o];
            v += __shfl_xor(v, 16, 64);
            v += __shfl_xor(v, 32, 64);
            p[cc][o] = v;
        }

    // --- bias + swish + store (q==0 lanes, static o indices) ---
    if (q == 0) {
        float* ob = out + ((size_t)(b * T_OUT + T_IN) * NNODES + n) * CC + 2 * c2;
#pragma unroll
        for (int o = 0; o < O_OUT; ++o) {
            float v0 = p[0][o] + bl_s[o];
            float v1 = p[1][o] + bl_s[o];
            float s0 = v0 / (1.f + expf(-0.8f * v0));
            float s1 = v1 / (1.f + expf(-0.8f * v1));
            *(float2*)(ob + (size_t)o * XSTRIDE) = make_float2(s0, s1);
        }
    }
}

extern "C" void kernel_launch(void* const* d_in, const int* in_sizes, int n_in,
                              void* d_out, int out_size, void* d_ws, size_t ws_size,
                              hipStream_t stream) {
    const float* x   = (const float*)d_in[0];
    const int*   nn  = (const int*)d_in[1];
    const float* nd  = (const float*)d_in[2];
    const float* Wsh = (const float*)d_in[3];
    const float* bsh = (const float*)d_in[4];
    float* out = (float*)d_out;
    unsigned* maxbits = (unsigned*)d_ws;

    hipMemsetAsync(d_ws, 0, sizeof(unsigned), stream);
    max_reduce_kernel<<<128, 256, 0, stream>>>(nd, NNODES * K1, maxbits);
    gnn_main_kernel<<<NNODES, 256, 0, stream>>>(x, nn, nd, Wsh, bsh, maxbits, out);
}

// Round 3
// 112.071 us; speedup vs baseline: 2.0042x; 1.0170x over previous
//
#include <hip/hip_runtime.h>

#define BB     4
#define T_IN   12
#define T_OUT  24
#define NNODES 5000
#define CC     32
#define HH     8
#define K1     17
#define O_OUT  12             // T_OUT - T_IN
#define XSTRIDE (NNODES*CC)   // floats per (b,t) plane
#define TPU     (NNODES*16)   // uints per (b,t) plane in bf16-packed x

// ---------------- kernel 1: global max over nearest_dists ----------------
__global__ void max_reduce_kernel(const float* __restrict__ d, int n,
                                  unsigned* __restrict__ out) {
    float m = 0.0f;  // dists >= 0
    for (int i = blockIdx.x * blockDim.x + threadIdx.x; i < n;
         i += gridDim.x * blockDim.x)
        m = fmaxf(m, d[i]);
#pragma unroll
    for (int off = 32; off > 0; off >>= 1)
        m = fmaxf(m, __shfl_down(m, off, 64));
    if ((threadIdx.x & 63) == 0)
        atomicMax(out, __float_as_uint(m));  // bit order == float order for >=0
}

// ---------------- kernel 2: prep = copy x -> out[:, :T_IN]  (+ bf16 pack) --
__device__ inline unsigned bf16rne(float f) {
    unsigned u = __float_as_uint(f);
    return (u + 0x7FFFu + ((u >> 16) & 1u)) >> 16;   // round-nearest-even
}

template <int PACK>
__global__ void prep_kernel(const float4* __restrict__ x,
                            float4* __restrict__ out,
                            uint2* __restrict__ xb) {
    const int PLANE4 = NNODES * CC / 4;       // 40000
    const int total  = BB * T_IN * PLANE4;    // 1,920,000
    for (int i = blockIdx.x * blockDim.x + threadIdx.x; i < total;
         i += gridDim.x * blockDim.x) {
        int bt = i / PLANE4;
        int qq = i - bt * PLANE4;
        int b  = bt / T_IN;
        int t  = bt - b * T_IN;
        float4 v = x[i];
        out[((size_t)(b * T_OUT + t)) * PLANE4 + qq] = v;
        if (PACK) {
            uint2 pk;
            pk.x = bf16rne(v.x) | (bf16rne(v.y) << 16);
            pk.y = bf16rne(v.z) | (bf16rne(v.w) << 16);
            xb[i] = pk;
        }
    }
}

// ---------------- kernel 3: gather-aggregate-shrink-swish ----------------
// One block per node n. rg = tid>>4 (0..15), c2 = tid&15.
//   b = rg>>2, q = rg&3, rows t = 3q+{0,1,2}; channels {2c2, 2c2+1}.
// Wave == batch b, so the q-reduction is shfl_xor(16/32).
template <int USEBF>
__launch_bounds__(256)
__global__ void gnn_main_kernel(const float* __restrict__ x,
                                const unsigned* __restrict__ xbu,
                                const int* __restrict__ nn,
                                const float* __restrict__ nd,
                                const float* __restrict__ Wsh,
                                const float* __restrict__ bsh,
                                const unsigned* __restrict__ maxbits,
                                float* __restrict__ out) {
    __shared__ float wl[K1][HH];     // GCN weights (544 B)
    __shared__ float Wl[96][O_OUT];  // W_shrink (4.5 KB)
    __shared__ float bl_s[O_OUT];
    __shared__ int   nnl[K1];

    const int n   = blockIdx.x;
    const int tid = threadIdx.x;
    const int rg  = tid >> 4;
    const int c2  = tid & 15;
    const int b   = rg >> 2;
    const int q   = rg & 3;

    // --- stage W_shrink (float4), bias, GCN weights, neighbor indices ---
    for (int i = tid; i < 288; i += 256)
        ((float4*)Wl)[i] = ((const float4*)Wsh)[i];
    if (tid < O_OUT) bl_s[tid] = bsh[tid];
    if (tid < K1 * HH) {
        int j = tid >> 3, h = tid & 7;
        int v = nn[n * K1 + j];
        float dv = nd[n * K1 + j];
        float mx = __uint_as_float(*maxbits);
        float inv_s2 = 4.0f / (mx * mx);          // 1/sigma^2, sigma = mx/2
        float lam = (float)(h + 1) * 0.125f;
        float wv = expf(-dv * dv * lam * inv_s2);
        if (v == -1 || wv < 1e-5f) wv = 0.0f;
        wl[j][h] = wv;
    }
    if (tid < K1) nnl[tid] = max(nn[n * K1 + tid], 0);  // -1 -> 0 (w already 0)
    __syncthreads();

    float acc[3][2][8];
#pragma unroll
    for (int k = 0; k < 3; ++k)
#pragma unroll
        for (int cc = 0; cc < 2; ++cc)
#pragma unroll
            for (int h = 0; h < 8; ++h) acc[k][cc][h] = 0.f;

    if (USEBF) {
        // ---- bf16 gather path: 1 dword per row, unpack lo/hi channels ----
        const unsigned* xbase = xbu + (b * T_IN + 3 * q) * TPU + c2;
        unsigned ua0, ua1, ua2, ub0, ub1, ub2;

#define LOADB(u0, u1, u2, J) do {                                            \
        int idx_ = __builtin_amdgcn_readfirstlane(nnl[(J)]);                 \
        const unsigned* bp_ = xbase + idx_ * 16;                             \
        u0 = bp_[0]; u1 = bp_[TPU]; u2 = bp_[2 * TPU];                       \
    } while (0)

#define COMPB(u0, u1, u2, J) do {                                            \
        float4 wA_ = *(const float4*)&wl[(J)][0];                            \
        float4 wB_ = *(const float4*)&wl[(J)][4];                            \
        float wv_[8] = {wA_.x, wA_.y, wA_.z, wA_.w,                          \
                        wB_.x, wB_.y, wB_.z, wB_.w};                         \
        float xl_[3] = {__uint_as_float(u0 << 16),                           \
                        __uint_as_float(u1 << 16),                           \
                        __uint_as_float(u2 << 16)};                          \
        float xh_[3] = {__uint_as_float(u0 & 0xffff0000u),                   \
                        __uint_as_float(u1 & 0xffff0000u),                   \
                        __uint_as_float(u2 & 0xffff0000u)};                  \
        _Pragma("unroll")                                                    \
        for (int k_ = 0; k_ < 3; ++k_)                                       \
            _Pragma("unroll")                                                \
            for (int h_ = 0; h_ < 8; ++h_) {                                 \
                acc[k_][0][h_] = fmaf(wv_[h_], xl_[k_], acc[k_][0][h_]);     \
                acc[k_][1][h_] = fmaf(wv_[h_], xh_[k_], acc[k_][1][h_]);     \
            }                                                                \
    } while (0)

        LOADB(ua0, ua1, ua2, 0);
#pragma unroll 1
        for (int jj = 0; jj < 8; ++jj) {
            LOADB(ub0, ub1, ub2, 2 * jj + 1);
            COMPB(ua0, ua1, ua2, 2 * jj);
            LOADB(ua0, ua1, ua2, 2 * jj + 2);   // jj=7 -> J=16 tail prefetch
            COMPB(ub0, ub1, ub2, 2 * jj + 1);
        }
        COMPB(ua0, ua1, ua2, 16);
#undef LOADB
#undef COMPB
    } else {
        // ---- fp32 fallback gather (ws too small for the bf16 mirror) ----
        const float* xbase = x + (b * T_IN + 3 * q) * XSTRIDE + 2 * c2;
        float2 xa0, xa1, xa2, xb0, xb1, xb2;

#define LOADJ(v0, v1, v2, J) do {                                            \
        int idx_ = __builtin_amdgcn_readfirstlane(nnl[(J)]);                 \
        const float* bp_ = xbase + idx_ * CC;                                \
        v0 = *(const float2*)(bp_);                                          \
        v1 = *(const float2*)(bp_ + XSTRIDE);                                \
        v2 = *(const float2*)(bp_ + 2 * XSTRIDE);                            \
    } while (0)

#define COMPJ(v0, v1, v2, J) do {                                            \
        float4 wA_ = *(const float4*)&wl[(J)][0];                            \
        float4 wB_ = *(const float4*)&wl[(J)][4];                            \
        float wv_[8] = {wA_.x, wA_.y, wA_.z, wA_.w,                          \
                        wB_.x, wB_.y, wB_.z, wB_.w};                         \
        float xv_[3][2] = {{v0.x, v0.y}, {v1.x, v1.y}, {v2.x, v2.y}};        \
        _Pragma("unroll")                                                    \
        for (int k_ = 0; k_ < 3; ++k_)                                       \
            _Pragma("unroll")                                                \
            for (int cc_ = 0; cc_ < 2; ++cc_)                                \
                _Pragma("unroll")                                            \
                for (int h_ = 0; h_ < 8; ++h_)                               \
                    acc[k_][cc_][h_] =                                       \
                        fmaf(wv_[h_], xv_[k_][cc_], acc[k_][cc_][h_]);       \
    } while (0)

        LOADJ(xa0, xa1, xa2, 0);
#pragma unroll 1
        for (int jj = 0; jj < 8; ++jj) {
            LOADJ(xb0, xb1, xb2, 2 * jj + 1);
            COMPJ(xa0, xa1, xa2, 2 * jj);
            LOADJ(xa0, xa1, xa2, 2 * jj + 2);
            COMPJ(xb0, xb1, xb2, 2 * jj + 1);
        }
        COMPJ(xa0, xa1, xa2, 16);
#undef LOADJ
#undef COMPJ
    }

    // --- fold acc against W_shrink: p[cc][o] = sum_{k,h} acc*W[(3q+k)*8+h][o]
    float p[2][O_OUT];
#pragma unroll
    for (int o = 0; o < O_OUT; ++o) { p[0][o] = 0.f; p[1][o] = 0.f; }

#pragma unroll
    for (int k = 0; k < 3; ++k) {
#pragma unroll
        for (int h = 0; h < 8; ++h) {
            int row = (3 * q + k) * 8 + h;
            const float4* wr = (const float4*)&Wl[row][0];  // 48B rows, aligned
            float4 w0 = wr[0], w1 = wr[1], w2 = wr[2];
            float wrow[12] = {w0.x, w0.y, w0.z, w0.w,
                              w1.x, w1.y, w1.z, w1.w,
                              w2.x, w2.y, w2.z, w2.w};
            float a0 = acc[k][0][h], a1 = acc[k][1][h];
#pragma unroll
            for (int o = 0; o < O_OUT; ++o) {
                p[0][o] = fmaf(a0, wrow[o], p[0][o]);
                p[1][o] = fmaf(a1, wrow[o], p[1][o]);
            }
        }
    }

    // --- q-reduction via wave butterfly (wave == batch b) ---
#pragma unroll
    for (int cc = 0; cc < 2; ++cc)
#pragma unroll
        for (int o = 0; o < O_OUT; ++o) {
            float v = p[cc][o];
            v += __shfl_xor(v, 16, 64);
            v += __shfl_xor(v, 32, 64);
            p[cc][o] = v;
        }

    // --- bias + swish + store (q==0 lanes) ---
    if (q == 0) {
        float* ob = out + ((size_t)(b * T_OUT + T_IN) * NNODES + n) * CC + 2 * c2;
#pragma unroll
        for (int o = 0; o < O_OUT; ++o) {
            float v0 = p[0][o] + bl_s[o];
            float v1 = p[1][o] + bl_s[o];
            float s0 = v0 / (1.f + expf(-0.8f * v0));
            float s1 = v1 / (1.f + expf(-0.8f * v1));
            *(float2*)(ob + (size_t)o * XSTRIDE) = make_float2(s0, s1);
        }
    }
}

extern "C" void kernel_launch(void* const* d_in, const int* in_sizes, int n_in,
                              void* d_out, int out_size, void* d_ws, size_t ws_size,
                              hipStream_t stream) {
    const float* x   = (const float*)d_in[0];
    const int*   nn  = (const int*)d_in[1];
    const float* nd  = (const float*)d_in[2];
    const float* Wsh = (const float*)d_in[3];
    const float* bsh = (const float*)d_in[4];
    float* out = (float*)d_out;

    unsigned* maxbits = (unsigned*)d_ws;
    unsigned* xbu     = (unsigned*)((char*)d_ws + 256);
    const size_t need = 256 + (size_t)BB * T_IN * NNODES * CC * 2;  // ~15.4 MB
    const bool usebf  = ws_size >= need;

    hipMemsetAsync(d_ws, 0, sizeof(unsigned), stream);
    max_reduce_kernel<<<128, 256, 0, stream>>>(nd, NNODES * K1, maxbits);

    if (usebf) {
        prep_kernel<1><<<2048, 256, 0, stream>>>((const float4*)x, (float4*)out,
                                                 (uint2*)xbu);
        gnn_main_kernel<1><<<NNODES, 256, 0, stream>>>(x, xbu, nn, nd, Wsh, bsh,
                                                       maxbits, out);
    } else {
        prep_kernel<0><<<2048, 256, 0, stream>>>((const float4*)x, (float4*)out,
                                                 (uint2*)xbu);
        gnn_main_kernel<0><<<NNODES, 256, 0, stream>>>(x, xbu, nn, nd, Wsh, bsh,
                                                       maxbits, out);
    }
}